// Round 1
// baseline (228.129 us; speedup 1.0000x reference)
//
#include <hip/hip_runtime.h>
#include <math.h>

#define N_NODES 100000
#define DIMS 128
#define RS 136   // W16 LDS row stride in halves (272 B): balanced-bank b128 reads
#define CS 136   // epilogue LDS row stride in halves

typedef _Float16 f16_t;
typedef f16_t half4 __attribute__((ext_vector_type(4)));
typedef f16_t half2_t __attribute__((ext_vector_type(2)));
typedef f16_t f16x8 __attribute__((ext_vector_type(8)));
typedef float f32x4 __attribute__((ext_vector_type(4)));

__device__ __forceinline__ f16x8 cvt8(float4 a, float4 b) {
    f16x8 h = { (f16_t)a.x, (f16_t)a.y, (f16_t)a.z, (f16_t)a.w,
                (f16_t)b.x, (f16_t)b.y, (f16_t)b.z, (f16_t)b.w };
    return h;
}

// wz16 = (fp16)(z @ W^T + b), z16 = (fp16)z, via mfma_f32_16x16x32_f16.
// R5 structure (LDS-staged fp16 W + fused A-frag/z16 emission) + R6's
// wave-local LDS-transpose epilogue (coalesced 16B wz16 stores, no barrier:
// same-wave DS ops are ordered and cl[wave] is wave-private).  [unchanged]
__global__ __launch_bounds__(256, 2)
void wz_kernel(const float* __restrict__ z, const float* __restrict__ W,
               const float* __restrict__ b,
               f16_t* __restrict__ z16, f16_t* __restrict__ wz16) {
    __shared__ f16_t wl[DIMS * RS];     // 34816 B
    __shared__ f16_t cl[4][16 * CS];    // 17408 B  (52.2 KB total)
    const int t    = threadIdx.x;
    const int lane = t & 63;
    const int wave = t >> 6;
    const int m    = lane & 15;
    const int quad = lane >> 4;

    // Stage W -> fp16 LDS: 128x128 = 4096 float4 chunks, 16 per thread.
    #pragma unroll
    for (int it = 0; it < 16; ++it) {
        int f  = it * 256 + t;
        int r  = f >> 5;             // W row (output col) 0..127
        int i4 = (f & 31) << 2;      // k offset 0..124
        float4 v = *(const float4*)(W + r * DIMS + i4);
        half4 h = { (f16_t)v.x, (f16_t)v.y, (f16_t)v.z, (f16_t)v.w };
        *(half4*)(wl + r * RS + i4) = h;
    }
    __syncthreads();

    const int r0    = blockIdx.x * 64 + wave * 16;   // wave's 16-row strip
    const int arow  = r0 + m;
    const int garow = arow < N_NODES ? arow : N_NODES - 1;   // clamp loads

    // A-frags for K=128 (4 chunks of 32), fused z16 emission.
    f16x8 afrag[4];
    #pragma unroll
    for (int c = 0; c < 4; ++c) {
        const int k0 = c * 32 + quad * 8;
        float4 v0 = *(const float4*)(z + (size_t)garow * DIMS + k0);
        float4 v1 = *(const float4*)(z + (size_t)garow * DIMS + k0 + 4);
        afrag[c] = cvt8(v0, v1);
        if (arow < N_NODES)
            *(f16x8*)(z16 + (size_t)arow * DIMS + k0) = afrag[c];
    }

    // 8 column tiles x 4 k-chunks of MFMA; B-frags from LDS.
    f32x4 acc[8];
    #pragma unroll
    for (int nt = 0; nt < 8; ++nt) acc[nt] = (f32x4){0.f, 0.f, 0.f, 0.f};

    #pragma unroll
    for (int nt = 0; nt < 8; ++nt) {
        #pragma unroll
        for (int c = 0; c < 4; ++c) {
            f16x8 bfrag = *(const f16x8*)(wl + (nt * 16 + m) * RS + c * 32 + quad * 8);
            acc[nt] = __builtin_amdgcn_mfma_f32_16x16x32_f16(afrag[c], bfrag, acc[nt], 0, 0, 0);
        }
    }

    // Epilogue: bias + cvt -> wave-local LDS transpose -> coalesced 16B stores.
    f16_t* my = cl[wave];
    #pragma unroll
    for (int nt = 0; nt < 8; ++nt) {
        const float bv = b[nt * 16 + m];
        #pragma unroll
        for (int r = 0; r < 4; ++r)
            my[(quad * 4 + r) * CS + nt * 16 + m] = (f16_t)(acc[nt][r] + bv);
    }
    #pragma unroll
    for (int p = 0; p < 4; ++p) {
        const int rr = p * 4 + (lane >> 4);
        const int cc = (lane & 15) * 8;
        const int gr = r0 + rr;
        if (gr < N_NODES)
            *(f16x8*)(wz16 + (size_t)gr * DIMS + cc) = *(const f16x8*)(my + rr * CS + cc);
    }
}

// Edge kernel v2: 16 lanes per edge, 16 B/lane gathers.
// - wave-uniform e0 (readfirstlane) -> index int4 loads scalarizable
// - 32-bit voffset addressing: (idx<<8)|(ls<<4) bytes, no 64-bit mul chain
// - packed v_dot2_f32_f16 for the partial dot (4 ops / 16 B pair)
// - 4-stage xor-shuffle reduce within the 16-lane group
__global__ __launch_bounds__(256)
void edge_kernel(const f16_t* __restrict__ z16, const f16_t* __restrict__ wz16,
                 const int* __restrict__ src, const int* __restrict__ dst,
                 float* __restrict__ out, int E) {
    const int wid = blockIdx.x * 4 + (threadIdx.x >> 6);   // wave id
    const int l   = threadIdx.x & 63;
    const int q   = l >> 4;        // edge slot within wave (0..3)
    const int ls  = l & 15;        // lane within edge group
    const int e0  = __builtin_amdgcn_readfirstlane(wid << 2);
    if (e0 >= E) return;

    const int4 s4 = *(const int4*)(src + e0);
    const int4 d4 = *(const int4*)(dst + e0);

    const int si = q == 0 ? s4.x : q == 1 ? s4.y : q == 2 ? s4.z : s4.w;
    const int di = q == 0 ? d4.x : q == 1 ? d4.y : q == 2 ? d4.z : d4.w;

    const unsigned lo = (unsigned)ls << 4;                 // byte offset in row
    f16x8 a = *(const f16x8*)((const char*)z16  + (((unsigned)si << 8) | lo));
    f16x8 w = *(const f16x8*)((const char*)wz16 + (((unsigned)di << 8) | lo));

    float p = 0.0f;
#if __has_builtin(__builtin_amdgcn_fdot2)
    const half2_t* ah = (const half2_t*)&a;
    const half2_t* wh = (const half2_t*)&w;
    #pragma unroll
    for (int i = 0; i < 4; ++i)
        p = __builtin_amdgcn_fdot2(ah[i], wh[i], p, false);
#else
    #pragma unroll
    for (int i = 0; i < 8; ++i)
        p = fmaf((float)a[i], (float)w[i], p);
#endif

    p += __shfl_xor(p, 8);
    p += __shfl_xor(p, 4);
    p += __shfl_xor(p, 2);
    p += __shfl_xor(p, 1);

    if (ls == 0) {
        const int e = e0 + q;
        if (e < E)
            out[e] = 1.0f / (1.0f + __expf(-p));
    }
}

extern "C" void kernel_launch(void* const* d_in, const int* in_sizes, int n_in,
                              void* d_out, int out_size, void* d_ws, size_t ws_size,
                              hipStream_t stream) {
    const float* z  = (const float*)d_in[0];
    const int*   ei = (const int*)d_in[1];   // [2, E] int32
    const float* W  = (const float*)d_in[2];
    const float* b  = (const float*)d_in[3];
    float* out = (float*)d_out;

    const int E = in_sizes[1] / 2;

    f16_t* z16  = (f16_t*)d_ws;                                       // 25.6 MB
    f16_t* wz16 = (f16_t*)((char*)d_ws + (size_t)N_NODES * DIMS * 2); // 25.6 MB

    const int row_blocks = (N_NODES + 63) / 64;     // 1563
    wz_kernel<<<row_blocks, 256, 0, stream>>>(z, W, b, z16, wz16);

    const int waves  = (E + 3) / 4;                 // 4 edges per wave
    const int blocks = (waves + 3) / 4;             // 4 waves per block
    edge_kernel<<<blocks, 256, 0, stream>>>(z16, wz16, ei, ei + E, out, E);
}

// Round 2
// 213.458 us; speedup vs baseline: 1.0687x; 1.0687x over previous
//
#include <hip/hip_runtime.h>
#include <math.h>

#define N_NODES 100000
#define DIMS 128
#define RS 136   // W16 LDS row stride in halves (272 B): balanced-bank b128 reads
#define CS 136   // epilogue LDS row stride in halves

typedef _Float16 f16_t;
typedef f16_t half4 __attribute__((ext_vector_type(4)));
typedef f16_t half2_t __attribute__((ext_vector_type(2)));
typedef f16_t f16x8 __attribute__((ext_vector_type(8)));
typedef float f32x4 __attribute__((ext_vector_type(4)));

__device__ __forceinline__ f16x8 cvt8(float4 a, float4 b) {
    f16x8 h = { (f16_t)a.x, (f16_t)a.y, (f16_t)a.z, (f16_t)a.w,
                (f16_t)b.x, (f16_t)b.y, (f16_t)b.z, (f16_t)b.w };
    return h;
}

// wz16 = (fp16)(z @ W^T + b), z16 = (fp16)z, via mfma_f32_16x16x32_f16.
// [unchanged — near its streaming floor]
__global__ __launch_bounds__(256, 2)
void wz_kernel(const float* __restrict__ z, const float* __restrict__ W,
               const float* __restrict__ b,
               f16_t* __restrict__ z16, f16_t* __restrict__ wz16) {
    __shared__ f16_t wl[DIMS * RS];     // 34816 B
    __shared__ f16_t cl[4][16 * CS];    // 17408 B  (52.2 KB total)
    const int t    = threadIdx.x;
    const int lane = t & 63;
    const int wave = t >> 6;
    const int m    = lane & 15;
    const int quad = lane >> 4;

    // Stage W -> fp16 LDS: 128x128 = 4096 float4 chunks, 16 per thread.
    #pragma unroll
    for (int it = 0; it < 16; ++it) {
        int f  = it * 256 + t;
        int r  = f >> 5;             // W row (output col) 0..127
        int i4 = (f & 31) << 2;      // k offset 0..124
        float4 v = *(const float4*)(W + r * DIMS + i4);
        half4 h = { (f16_t)v.x, (f16_t)v.y, (f16_t)v.z, (f16_t)v.w };
        *(half4*)(wl + r * RS + i4) = h;
    }
    __syncthreads();

    const int r0    = blockIdx.x * 64 + wave * 16;   // wave's 16-row strip
    const int arow  = r0 + m;
    const int garow = arow < N_NODES ? arow : N_NODES - 1;   // clamp loads

    // A-frags for K=128 (4 chunks of 32), fused z16 emission.
    f16x8 afrag[4];
    #pragma unroll
    for (int c = 0; c < 4; ++c) {
        const int k0 = c * 32 + quad * 8;
        float4 v0 = *(const float4*)(z + (size_t)garow * DIMS + k0);
        float4 v1 = *(const float4*)(z + (size_t)garow * DIMS + k0 + 4);
        afrag[c] = cvt8(v0, v1);
        if (arow < N_NODES)
            *(f16x8*)(z16 + (size_t)arow * DIMS + k0) = afrag[c];
    }

    // 8 column tiles x 4 k-chunks of MFMA; B-frags from LDS.
    f32x4 acc[8];
    #pragma unroll
    for (int nt = 0; nt < 8; ++nt) acc[nt] = (f32x4){0.f, 0.f, 0.f, 0.f};

    #pragma unroll
    for (int nt = 0; nt < 8; ++nt) {
        #pragma unroll
        for (int c = 0; c < 4; ++c) {
            f16x8 bfrag = *(const f16x8*)(wl + (nt * 16 + m) * RS + c * 32 + quad * 8);
            acc[nt] = __builtin_amdgcn_mfma_f32_16x16x32_f16(afrag[c], bfrag, acc[nt], 0, 0, 0);
        }
    }

    // Epilogue: bias + cvt -> wave-local LDS transpose -> coalesced 16B stores.
    f16_t* my = cl[wave];
    #pragma unroll
    for (int nt = 0; nt < 8; ++nt) {
        const float bv = b[nt * 16 + m];
        #pragma unroll
        for (int r = 0; r < 4; ++r)
            my[(quad * 4 + r) * CS + nt * 16 + m] = (f16_t)(acc[nt][r] + bv);
    }
    #pragma unroll
    for (int p = 0; p < 4; ++p) {
        const int rr = p * 4 + (lane >> 4);
        const int cc = (lane & 15) * 8;
        const int gr = r0 + rr;
        if (gr < N_NODES)
            *(f16x8*)(wz16 + (size_t)gr * DIMS + cc) = *(const f16x8*)(my + rr * CS + cc);
    }
}

// Edge kernel v3: 16 edges per wave, 16 lanes per edge, 16 B/lane gathers.
// v2's cheap addressing (32-bit voffset, uniform index loads, fdot2) PLUS
// v1-beating MLP: all 8 gathers (8 KB/wave) issued before any compute.
// (v2 regression root cause: only 2 outstanding loads/wave -> latency-bound.)
__global__ __launch_bounds__(256)
void edge_kernel(const f16_t* __restrict__ z16, const f16_t* __restrict__ wz16,
                 const int* __restrict__ src, const int* __restrict__ dst,
                 float* __restrict__ out, int E) {
    const int wid = blockIdx.x * 4 + (threadIdx.x >> 6);   // wave id
    const int l   = threadIdx.x & 63;
    const int q   = l >> 4;        // edge slot within round (0..3)
    const int ls  = l & 15;        // lane within edge group
    const int e0  = __builtin_amdgcn_readfirstlane(wid << 4);   // 16 edges/wave
    if (e0 >= E) return;

    const unsigned lo = (unsigned)ls << 4;   // byte offset within 256-B row

    // Batch-issue all 8 gathers (4 rounds x {z,wz}): 8 outstanding vmem/lane.
    f16x8 a[4], w[4];
    #pragma unroll
    for (int r = 0; r < 4; ++r) {
        const int4 s4 = *(const int4*)(src + e0 + r * 4);   // uniform -> s_load
        const int4 d4 = *(const int4*)(dst + e0 + r * 4);
        const int si = q == 0 ? s4.x : q == 1 ? s4.y : q == 2 ? s4.z : s4.w;
        const int di = q == 0 ? d4.x : q == 1 ? d4.y : q == 2 ? d4.z : d4.w;
        a[r] = *(const f16x8*)((const char*)z16  + (((unsigned)si << 8) | lo));
        w[r] = *(const f16x8*)((const char*)wz16 + (((unsigned)di << 8) | lo));
    }

    #pragma unroll
    for (int r = 0; r < 4; ++r) {
        float p = 0.0f;
#if __has_builtin(__builtin_amdgcn_fdot2)
        const half2_t* ah = (const half2_t*)&a[r];
        const half2_t* wh = (const half2_t*)&w[r];
        #pragma unroll
        for (int i = 0; i < 4; ++i)
            p = __builtin_amdgcn_fdot2(ah[i], wh[i], p, false);
#else
        #pragma unroll
        for (int i = 0; i < 8; ++i)
            p = fmaf((float)a[r][i], (float)w[r][i], p);
#endif
        p += __shfl_xor(p, 8);
        p += __shfl_xor(p, 4);
        p += __shfl_xor(p, 2);
        p += __shfl_xor(p, 1);

        if (ls == 0) {
            const int e = e0 + r * 4 + q;
            if (e < E)
                out[e] = 1.0f / (1.0f + __expf(-p));
        }
    }
}

extern "C" void kernel_launch(void* const* d_in, const int* in_sizes, int n_in,
                              void* d_out, int out_size, void* d_ws, size_t ws_size,
                              hipStream_t stream) {
    const float* z  = (const float*)d_in[0];
    const int*   ei = (const int*)d_in[1];   // [2, E] int32
    const float* W  = (const float*)d_in[2];
    const float* b  = (const float*)d_in[3];
    float* out = (float*)d_out;

    const int E = in_sizes[1] / 2;

    f16_t* z16  = (f16_t*)d_ws;                                       // 25.6 MB
    f16_t* wz16 = (f16_t*)((char*)d_ws + (size_t)N_NODES * DIMS * 2); // 25.6 MB

    const int row_blocks = (N_NODES + 63) / 64;     // 1563
    wz_kernel<<<row_blocks, 256, 0, stream>>>(z, W, b, z16, wz16);

    const int waves  = (E + 15) / 16;               // 16 edges per wave
    const int blocks = (waves + 3) / 4;             // 4 waves per block
    edge_kernel<<<blocks, 256, 0, stream>>>(z16, wz16, ei, ei + E, out, E);
}